// Round 12
// baseline (434.198 us; speedup 1.0000x reference)
//
#include <hip/hip_runtime.h>
#include <stdint.h>

#define N_NODES 20000
#define N_EDGES 320000
#define E_TOT   340000
#define NGRAPH  128
#define F       512
#define M_PAD   20096     // 157*128
#define NEG_SLOPE 0.2f

typedef __bf16 bf16x8 __attribute__((ext_vector_type(8)));
typedef float  f32x4  __attribute__((ext_vector_type(4)));

// ---------------- workspace layout (bytes; all 128-aligned) ----------------
#define WS_WT0   0UL            // 131,072   (bf16 W0^T, K padded 79->128)
#define WS_WT1   131072UL       // 524,288
#define WS_WT2   655360UL       // 524,288
#define WS_HMID  1179648UL      // 20,578,304  (bf16 [M_PAD][512])
#define WS_HA    21757952UL     // 20,578,304
#define WS_ALS   42336256UL     // 640,000  (fp32 [N][8])
#define WS_ALD   42976256UL     // 640,000
#define WS_CNT   43616256UL     // 80,000
#define WS_CUR   43696256UL     // 80,000
#define WS_RP    43776256UL     // 80,128
#define WS_BTOT  43856384UL     // 512
#define WS_BOFF  43856896UL     // 512
#define WS_CSRC  43857408UL     // 1,360,000  (src node id per CSR slot)
#define WS_G     45217408UL     // 262,144  (fp32 [128][512])
#define WS_EI32  45479552UL     // 2,560,000
#define WS_B32   48039552UL     // 80,000
#define WS_CDST  48119552UL     // 1,360,000  (dst node id per CSR slot)
#define WS_EW    49479552UL     // 10,880,000 (fp32 edge weights [slot][8])
// total ~60.4 MB (proven OK)

__device__ __forceinline__ float b2f(uint16_t u) {
    union { uint32_t i; float f; } v; v.i = ((uint32_t)u) << 16; return v.f;
}
__device__ __forceinline__ uint16_t f2b(float f) {
    union { float f; uint32_t i; } v; v.f = f;
    uint32_t x = v.i;
    return (uint16_t)((x + 0x7FFFu + ((x >> 16) & 1u)) >> 16);   // RNE
}
__device__ __forceinline__ void gload_lds16(const void* g, void* l) {
    __builtin_amdgcn_global_load_lds((const __attribute__((address_space(1))) uint32_t*)g,
                                     (__attribute__((address_space(3))) uint32_t*)l,
                                     16, 0, 0);
}

__global__ void canary_kernel(float* __restrict__ out, int n) {
    int i = threadIdx.x;
    if (i < n) out[i] = 64.0f;
}

// zero count/cursor + gbuf (harness poisons ws before every launch)
__global__ void zero_ws_kernel(int* __restrict__ cnt, int* __restrict__ cur,
                               float* __restrict__ gbuf) {
    int i = blockIdx.x * 256 + threadIdx.x;
    if (i < N_NODES) { cnt[i] = 0; cur[i] = 0; }
    else {
        int j = i - N_NODES;
        if (j < NGRAPH * F) gbuf[j] = 0.f;
    }
}

// ---------------- int64/int32 detection + conversion ----------------
__global__ void cvt_idx_kernel(const int* __restrict__ raw_ei, const int* __restrict__ raw_batch,
                               int* __restrict__ ei32, int* __restrict__ b32) {
    int i = blockIdx.x * 256 + threadIdx.x;
    int is64 = ((raw_ei[1] | raw_ei[3] | raw_ei[5] | raw_ei[7] |
                 raw_ei[9] | raw_ei[11] | raw_ei[13] | raw_ei[15]) == 0) ? 1 : 0;
    if (i < 2 * N_EDGES) {
        ei32[i] = is64 ? raw_ei[2 * i] : raw_ei[i];
    } else {
        int j = i - 2 * N_EDGES;
        if (j < N_NODES) b32[j] = is64 ? raw_batch[2 * j] : raw_batch[j];
    }
}

// ---------------- W[K][512] fp32 -> Wt[512][KP] bf16 (zero-pad K->KP) -------
__global__ void transpose_w_kernel(const float* __restrict__ W, uint16_t* __restrict__ Wt,
                                   int K, int KP) {
    int i = blockIdx.x * 256 + threadIdx.x;
    if (i >= F * KP) return;
    int n = i / KP, k = i - n * KP;
    Wt[i] = (k < K) ? f2b(W[(size_t)k * F + n]) : (uint16_t)0;
}

// ---------------- MFMA GEMM: C[M_PAD][512] = A[..][K] * Wt[512][KP]^T -------
template <bool AF32>
__global__ __launch_bounds__(256) void gemm_mfma_kernel(
    const void* __restrict__ Av, const uint16_t* __restrict__ Bt,
    uint16_t* __restrict__ C, int M, int K, int KP)
{
    __shared__ uint16_t Alds[128 * 64];
    __shared__ uint16_t Blds[128 * 64];

    const int tid = threadIdx.x;
    const int w = tid >> 6, l = tid & 63;
    const int wr = w >> 1, wc = w & 1;
    const int m0 = blockIdx.x * 128, n0 = blockIdx.y * 128;

    f32x4 acc[4][4];
#pragma unroll
    for (int m = 0; m < 4; ++m)
#pragma unroll
        for (int n = 0; n < 4; ++n) acc[m][n] = (f32x4){0.f, 0.f, 0.f, 0.f};

    const int row_s = (l >> 3);
    const int kof_s = (l & 7) * 8;

    for (int k0 = 0; k0 < KP; k0 += 64) {
        if (AF32) {
            uint4 ta[4];
#pragma unroll
            for (int i = 0; i < 4; ++i) {
                int c = w * 4 + i;
                int ar = m0 + c * 8 + row_s;
                union { uint16_t u[8]; uint4 v; } tmp;
#pragma unroll
                for (int j = 0; j < 8; ++j) {
                    int k = k0 + kof_s + j;
                    float fv = (ar < M && k < K) ? ((const float*)Av)[(size_t)ar * K + k] : 0.f;
                    tmp.u[j] = f2b(fv);
                }
                ta[i] = tmp.v;
            }
            __syncthreads();
#pragma unroll
            for (int i = 0; i < 4; ++i) {
                int c = w * 4 + i;
                *(uint4*)&Alds[c * 512 + l * 8] = ta[i];
                gload_lds16(Bt + (size_t)(n0 + c * 8 + row_s) * KP + k0 + kof_s, &Blds[c * 512]);
            }
            __syncthreads();
        } else {
            __syncthreads();
#pragma unroll
            for (int i = 0; i < 4; ++i) {
                int c = w * 4 + i;                    // chunk 0..15 (wave-uniform LDS base)
                int trow = c * 8 + row_s;             // per-lane global row
                gload_lds16((const uint16_t*)Av + (size_t)(m0 + trow) * K + k0 + kof_s, &Alds[c * 512]);
                gload_lds16(Bt + (size_t)(n0 + trow) * KP + k0 + kof_s, &Blds[c * 512]);
            }
            __syncthreads();
        }
#pragma unroll
        for (int kk = 0; kk < 2; ++kk) {
            const int koff = kk * 32 + (l >> 4) * 8;
            bf16x8 af[4], bfr[4];
#pragma unroll
            for (int m = 0; m < 4; ++m) {
                int row = wr * 64 + m * 16 + (l & 15);
                af[m] = *(const bf16x8*)&Alds[row * 64 + koff];
            }
#pragma unroll
            for (int n = 0; n < 4; ++n) {
                int col = wc * 64 + n * 16 + (l & 15);
                bfr[n] = *(const bf16x8*)&Blds[col * 64 + koff];
            }
#pragma unroll
            for (int m = 0; m < 4; ++m)
#pragma unroll
                for (int n = 0; n < 4; ++n)
                    acc[m][n] = __builtin_amdgcn_mfma_f32_16x16x32_bf16(af[m], bfr[n], acc[m][n], 0, 0, 0);
        }
    }

    // C/D layout (m89-verified): col = lane&15, row = (lane>>4)*4 + j
#pragma unroll
    for (int m = 0; m < 4; ++m) {
        int rb = m0 + wr * 64 + m * 16 + ((l >> 4) << 2);
#pragma unroll
        for (int n = 0; n < 4; ++n) {
            int col = n0 + wc * 64 + n * 16 + (l & 15);
#pragma unroll
            for (int j = 0; j < 4; ++j)
                C[(size_t)(rb + j) * F + col] = f2b(acc[m][n][j]);
        }
    }
}

// ---------------- per-node attention logits ----------------
__global__ void alpha_kernel(const uint16_t* __restrict__ h,
                             const float* __restrict__ asrc, const float* __restrict__ adst,
                             float* __restrict__ als, float* __restrict__ ald)
{
    int gt = blockIdx.x * 256 + threadIdx.x;
    int wv = gt >> 6, l = threadIdx.x & 63;
    if (wv >= N_NODES) return;
    const uint4 hv = *(const uint4*)(h + (size_t)wv * F + l * 8);
    uint32_t hw[4] = {hv.x, hv.y, hv.z, hv.w};
    float hf[8];
#pragma unroll
    for (int j = 0; j < 4; ++j) {
        hf[2 * j]     = b2f((uint16_t)(hw[j] & 0xFFFF));
        hf[2 * j + 1] = b2f((uint16_t)(hw[j] >> 16));
    }
    float ps = 0.f, pd = 0.f;
#pragma unroll
    for (int j = 0; j < 8; ++j) {
        ps += hf[j] * asrc[l * 8 + j];
        pd += hf[j] * adst[l * 8 + j];
    }
#pragma unroll
    for (int s = 1; s < 8; s <<= 1) {
        ps += __shfl_xor(ps, s, 64);
        pd += __shfl_xor(pd, s, 64);
    }
    if ((l & 7) == 0) {
        int hd = l >> 3;
        als[(size_t)wv * 8 + hd] = ps;
        ald[(size_t)wv * 8 + hd] = pd;
    }
}

// ---------------- CSR build ----------------
__global__ void hist_kernel(const int* __restrict__ ei, int* __restrict__ count) {
    int e = blockIdx.x * 256 + threadIdx.x;
    if (e >= E_TOT) return;
    int dst = (e < N_EDGES) ? ei[N_EDGES + e] : e - N_EDGES;
    atomicAdd(&count[dst], 1);
}

__global__ void scan1_kernel(const int* __restrict__ count, int* __restrict__ rp, int* __restrict__ btot) {
    __shared__ int s[256];
    int t = threadIdx.x, i = blockIdx.x * 256 + t;
    int v = (i < N_NODES) ? count[i] : 0;
    s[t] = v; __syncthreads();
    for (int off = 1; off < 256; off <<= 1) {
        int x = (t >= off) ? s[t - off] : 0; __syncthreads();
        s[t] += x; __syncthreads();
    }
    if (i < N_NODES) rp[i] = s[t] - v;
    if (t == 255) btot[blockIdx.x] = s[255];
}

__global__ void scan2_kernel(int* __restrict__ btot, int* __restrict__ boff) {
    __shared__ int s[128];
    int t = threadIdx.x;
    int v = (t < 79) ? btot[t] : 0;
    s[t] = v; __syncthreads();
    for (int off = 1; off < 128; off <<= 1) {
        int x = (t >= off) ? s[t - off] : 0; __syncthreads();
        s[t] += x; __syncthreads();
    }
    if (t < 79) boff[t] = s[t] - v;
}

__global__ void scan3_kernel(int* __restrict__ rp, const int* __restrict__ boff) {
    int i = blockIdx.x * 256 + threadIdx.x;
    if (i >= N_NODES) return;
    rp[i] += boff[i >> 8];
    if (i == 0) rp[N_NODES] = E_TOT;
}

// store src AND dst node id per CSR slot
__global__ void scatter_kernel(const int* __restrict__ ei, const int* __restrict__ rp,
                               int* __restrict__ cursor, int* __restrict__ csrc,
                               int* __restrict__ cdst) {
    int e = blockIdx.x * 256 + threadIdx.x;
    if (e >= E_TOT) return;
    int src, dst;
    if (e < N_EDGES) { src = ei[e]; dst = ei[N_EDGES + e]; }
    else { src = dst = e - N_EDGES; }
    int pos = atomicAdd(&cursor[dst], 1);
    csrc[rp[dst] + pos] = src;
    cdst[rp[dst] + pos] = dst;
}

// ---------------- per-slot edge weights: ew = exp(leakyrelu(als[s]+ald[d])) --
__global__ void ew_kernel(const int* __restrict__ csrc, const int* __restrict__ cdst,
                          const float* __restrict__ als, const float* __restrict__ ald,
                          float* __restrict__ ew)
{
    int i = blockIdx.x * 256 + threadIdx.x;
    if (i >= E_TOT) return;
    int s = csrc[i], d = cdst[i];
    float4 a0 = *(const float4*)(als + (size_t)s * 8);
    float4 a1 = *(const float4*)(als + (size_t)s * 8 + 4);
    float4 d0 = *(const float4*)(ald + (size_t)d * 8);
    float4 d1 = *(const float4*)(ald + (size_t)d * 8 + 4);
    float v[8] = {a0.x + d0.x, a0.y + d0.y, a0.z + d0.z, a0.w + d0.w,
                  a1.x + d1.x, a1.y + d1.y, a1.z + d1.z, a1.w + d1.w};
#pragma unroll
    for (int hh = 0; hh < 8; ++hh) {
        float xg = v[hh];
        xg = (xg > 0.f) ? xg : NEG_SLOPE * xg;
        v[hh] = __expf(xg);
    }
    float4* o = (float4*)(ew + (size_t)i * 8);
    o[0] = make_float4(v[0], v[1], v[2], v[3]);
    o[1] = make_float4(v[4], v[5], v[6], v[7]);
}

// -------- aggregation: 2 nodes/block, 128 thr/node, 4 ch/thread (8B loads) --
__global__ __launch_bounds__(256) void agg_kernel(
    const uint16_t* __restrict__ h,
    const int* __restrict__ rp, const int* __restrict__ csrc,
    const float* __restrict__ ew,
    const float* __restrict__ bias, uint16_t* __restrict__ out)
{
    const int tl = threadIdx.x & 127;
    const int n = blockIdx.x * 2 + (threadIdx.x >> 7);
    const int c0 = tl * 4, hd = tl >> 4;     // head = c0>>6
    int rs = rp[n], re = rp[n + 1];
    float a0 = 0.f, a1 = 0.f, a2 = 0.f, a3 = 0.f, dsum = 0.f;
    int idx = rs;
    for (; idx + 8 <= re; idx += 8) {
        int s[8]; float w[8]; uint2 v[8];
#pragma unroll
        for (int j = 0; j < 8; ++j) s[j] = csrc[idx + j];
#pragma unroll
        for (int j = 0; j < 8; ++j) w[j] = ew[(size_t)(idx + j) * 8 + hd];
#pragma unroll
        for (int j = 0; j < 8; ++j) v[j] = *(const uint2*)(h + (size_t)s[j] * F + c0);
#pragma unroll
        for (int j = 0; j < 8; ++j) {
            dsum += w[j];
            a0 += w[j] * b2f((uint16_t)(v[j].x & 0xFFFF));
            a1 += w[j] * b2f((uint16_t)(v[j].x >> 16));
            a2 += w[j] * b2f((uint16_t)(v[j].y & 0xFFFF));
            a3 += w[j] * b2f((uint16_t)(v[j].y >> 16));
        }
    }
    if (idx + 4 <= re) {
        int s[4]; float w[4]; uint2 v[4];
#pragma unroll
        for (int j = 0; j < 4; ++j) s[j] = csrc[idx + j];
#pragma unroll
        for (int j = 0; j < 4; ++j) w[j] = ew[(size_t)(idx + j) * 8 + hd];
#pragma unroll
        for (int j = 0; j < 4; ++j) v[j] = *(const uint2*)(h + (size_t)s[j] * F + c0);
#pragma unroll
        for (int j = 0; j < 4; ++j) {
            dsum += w[j];
            a0 += w[j] * b2f((uint16_t)(v[j].x & 0xFFFF));
            a1 += w[j] * b2f((uint16_t)(v[j].x >> 16));
            a2 += w[j] * b2f((uint16_t)(v[j].y & 0xFFFF));
            a3 += w[j] * b2f((uint16_t)(v[j].y >> 16));
        }
        idx += 4;
    }
    for (; idx < re; ++idx) {
        int s = csrc[idx];
        float wgt = ew[(size_t)idx * 8 + hd];
        dsum += wgt;
        uint2 hv = *(const uint2*)(h + (size_t)s * F + c0);
        a0 += wgt * b2f((uint16_t)(hv.x & 0xFFFF));
        a1 += wgt * b2f((uint16_t)(hv.x >> 16));
        a2 += wgt * b2f((uint16_t)(hv.y & 0xFFFF));
        a3 += wgt * b2f((uint16_t)(hv.y >> 16));
    }
    float inv = 1.0f / dsum;
    float o0 = a0 * inv + bias[c0];
    float o1 = a1 * inv + bias[c0 + 1];
    float o2 = a2 * inv + bias[c0 + 2];
    float o3 = a3 * inv + bias[c0 + 3];
    o0 = o0 > 0.f ? o0 : 0.f;
    o1 = o1 > 0.f ? o1 : 0.f;
    o2 = o2 > 0.f ? o2 : 0.f;
    o3 = o3 > 0.f ? o3 : 0.f;
    uint2 pk;
    pk.x = (uint32_t)f2b(o0) | ((uint32_t)f2b(o1) << 16);
    pk.y = (uint32_t)f2b(o2) | ((uint32_t)f2b(o3) << 16);
    *(uint2*)(out + (size_t)n * F + c0) = pk;
}

// ---------------- pooling (parallelized: grid (NGRAPH, 8) + atomics) --------
__device__ __forceinline__ int lbound(const int* arr, int n, int key) {
    int lo = 0, hi = n;
    while (lo < hi) { int mid = (lo + hi) >> 1; if (arr[mid] < key) lo = mid + 1; else hi = mid; }
    return lo;
}

__global__ __launch_bounds__(256) void pool_kernel(
    const uint16_t* __restrict__ h, const int* __restrict__ batch,
    float* __restrict__ g)
{
    int gr = blockIdx.x, chunk = blockIdx.y, t = threadIdx.x;
    int s = lbound(batch, N_NODES, gr);
    int e = lbound(batch, N_NODES, gr + 1);
    int len = e - s;
    int cs = s + (len * chunk) / 8;
    int ce = s + (len * (chunk + 1)) / 8;
    if (cs >= ce) return;
    int c0 = t * 2;
    float a0 = 0.f, a1 = 0.f;
    for (int n = cs; n < ce; ++n) {
        uint32_t hv = *(const uint32_t*)(h + (size_t)n * F + c0);
        a0 += b2f((uint16_t)(hv & 0xFFFF));
        a1 += b2f((uint16_t)(hv >> 16));
    }
    atomicAdd(&g[(size_t)gr * F + c0], a0);
    atomicAdd(&g[(size_t)gr * F + c0 + 1], a1);
}

__global__ void mlp_kernel(
    const float* __restrict__ g,
    const float* __restrict__ l1w, const float* __restrict__ l1b,
    const float* __restrict__ l2w, const float* __restrict__ l2b,
    float* __restrict__ out)
{
    __shared__ float gr[512];
    int b = blockIdx.x, t = threadIdx.x;
    for (int i = t; i < 512; i += 64) gr[i] = g[(size_t)b * F + i];
    __syncthreads();
    float acc = l1b[t];
    for (int k = 0; k < 512; ++k) acc += gr[k] * l1w[k * 64 + t];
    acc = acc > 0.f ? acc : 0.f;
    float v = acc * l2w[t];
#pragma unroll
    for (int s = 1; s < 64; s <<= 1) v += __shfl_xor(v, s, 64);
    if (t == 0) out[b] = v + l2b[0];
}

// ---------------- host ----------------
extern "C" void kernel_launch(void* const* d_in, const int* in_sizes, int n_in,
                              void* d_out, int out_size, void* d_ws, size_t ws_size,
                              hipStream_t stream) {
    const float* x   = (const float*)d_in[0];
    const float* W0  = (const float*)d_in[1];
    const float* as0 = (const float*)d_in[2];
    const float* ad0 = (const float*)d_in[3];
    const float* b0  = (const float*)d_in[4];
    const float* W1  = (const float*)d_in[5];
    const float* as1 = (const float*)d_in[6];
    const float* ad1 = (const float*)d_in[7];
    const float* b1  = (const float*)d_in[8];
    const float* W2  = (const float*)d_in[9];
    const float* as2 = (const float*)d_in[10];
    const float* ad2 = (const float*)d_in[11];
    const float* b2  = (const float*)d_in[12];
    const float* l1w = (const float*)d_in[13];
    const float* l1b = (const float*)d_in[14];
    const float* l2w = (const float*)d_in[15];
    const float* l2b = (const float*)d_in[16];
    const int* ei_raw    = (const int*)d_in[17];
    const int* batch_raw = (const int*)d_in[18];

    char* ws = (char*)d_ws;
    uint16_t* wt0  = (uint16_t*)(ws + WS_WT0);
    uint16_t* wt1  = (uint16_t*)(ws + WS_WT1);
    uint16_t* wt2  = (uint16_t*)(ws + WS_WT2);
    uint16_t* hmid = (uint16_t*)(ws + WS_HMID);
    uint16_t* hA   = (uint16_t*)(ws + WS_HA);
    float* als  = (float*)(ws + WS_ALS);
    float* ald  = (float*)(ws + WS_ALD);
    int* count  = (int*)(ws + WS_CNT);
    int* cursor = (int*)(ws + WS_CUR);
    int* rp     = (int*)(ws + WS_RP);
    int* btot   = (int*)(ws + WS_BTOT);
    int* boff   = (int*)(ws + WS_BOFF);
    int* csrc   = (int*)(ws + WS_CSRC);
    float* gbuf = (float*)(ws + WS_G);
    int* ei32   = (int*)(ws + WS_EI32);
    int* b32    = (int*)(ws + WS_B32);
    int* cdst   = (int*)(ws + WS_CDST);
    float* ew   = (float*)(ws + WS_EW);
    float* out  = (float*)d_out;

    canary_kernel<<<1, 128, 0, stream>>>(out, out_size);
    zero_ws_kernel<<<(N_NODES + NGRAPH * F + 255) / 256, 256, 0, stream>>>(count, cursor, gbuf);
    cvt_idx_kernel<<<(2 * N_EDGES + N_NODES + 255) / 256, 256, 0, stream>>>(ei_raw, batch_raw, ei32, b32);

    // weights -> bf16 transposed
    transpose_w_kernel<<<(F * 128) / 256, 256, 0, stream>>>(W0, wt0, 79, 128);
    transpose_w_kernel<<<(F * F) / 256, 256, 0, stream>>>(W1, wt1, F, F);
    transpose_w_kernel<<<(F * F) / 256, 256, 0, stream>>>(W2, wt2, F, F);

    // CSR (structure fixed across layers)
    int eb = (E_TOT + 255) / 256;
    hist_kernel<<<eb, 256, 0, stream>>>(ei32, count);
    scan1_kernel<<<79, 256, 0, stream>>>(count, rp, btot);
    scan2_kernel<<<1, 128, 0, stream>>>(btot, boff);
    scan3_kernel<<<79, 256, 0, stream>>>(rp, boff);
    scatter_kernel<<<eb, 256, 0, stream>>>(ei32, rp, cursor, csrc, cdst);

    dim3 gg(M_PAD / 128, F / 128);

    // layer 0 (fp32 x, K=79 padded to 128)
    gemm_mfma_kernel<true><<<gg, 256, 0, stream>>>(x, wt0, hmid, N_NODES, 79, 128);
    alpha_kernel<<<(N_NODES * 64) / 256, 256, 0, stream>>>(hmid, as0, ad0, als, ald);
    ew_kernel<<<eb, 256, 0, stream>>>(csrc, cdst, als, ald, ew);
    agg_kernel<<<N_NODES / 2, 256, 0, stream>>>(hmid, rp, csrc, ew, b0, hA);

    // layer 1
    gemm_mfma_kernel<false><<<gg, 256, 0, stream>>>(hA, wt1, hmid, M_PAD, F, F);
    alpha_kernel<<<(N_NODES * 64) / 256, 256, 0, stream>>>(hmid, as1, ad1, als, ald);
    ew_kernel<<<eb, 256, 0, stream>>>(csrc, cdst, als, ald, ew);
    agg_kernel<<<N_NODES / 2, 256, 0, stream>>>(hmid, rp, csrc, ew, b1, hA);

    // layer 2
    gemm_mfma_kernel<false><<<gg, 256, 0, stream>>>(hA, wt2, hmid, M_PAD, F, F);
    alpha_kernel<<<(N_NODES * 64) / 256, 256, 0, stream>>>(hmid, as2, ad2, als, ald);
    ew_kernel<<<eb, 256, 0, stream>>>(csrc, cdst, als, ald, ew);
    agg_kernel<<<N_NODES / 2, 256, 0, stream>>>(hmid, rp, csrc, ew, b2, hA);

    dim3 gp(NGRAPH, 8);
    pool_kernel<<<gp, 256, 0, stream>>>(hA, b32, gbuf);
    mlp_kernel<<<NGRAPH, 64, 0, stream>>>(gbuf, l1w, l1b, l2w, l2b, out);
}

// Round 13
// 419.109 us; speedup vs baseline: 1.0360x; 1.0360x over previous
//
#include <hip/hip_runtime.h>
#include <stdint.h>

#define N_NODES 20000
#define N_EDGES 320000
#define E_TOT   340000
#define NGRAPH  128
#define F       512
#define M_PAD   20096     // 157*128
#define NEG_SLOPE 0.2f

typedef __bf16 bf16x8 __attribute__((ext_vector_type(8)));
typedef float  f32x4  __attribute__((ext_vector_type(4)));

// ---------------- workspace layout (bytes; all 128-aligned) ----------------
#define WS_WT0   0UL            // 131,072   (bf16 W0^T, K padded 79->128)
#define WS_WT1   131072UL       // 524,288
#define WS_WT2   655360UL       // 524,288
#define WS_HMID  1179648UL      // 20,578,304  (bf16 [M_PAD][512])
#define WS_HA    21757952UL     // 20,578,304
#define WS_ALS   42336256UL     // 640,000  (fp32 [N][8])
#define WS_ALD   42976256UL     // 640,000
#define WS_CNT   43616256UL     // 80,000
#define WS_CUR   43696256UL     // 80,000
#define WS_RP    43776256UL     // 80,128
#define WS_BTOT  43856384UL     // 512
#define WS_BOFF  43856896UL     // 512
#define WS_CSRC  43857408UL     // 1,360,000  (src node id per CSR slot)
#define WS_G     45217408UL     // 262,144  (fp32 [128][512])
#define WS_EI32  45479552UL     // 2,560,000
#define WS_B32   48039552UL     // 80,000
#define WS_CDST  48119552UL     // 1,360,000  (dst node id per CSR slot)
#define WS_EW    49479552UL     // 10,880,000 (fp32 edge weights [slot][8])
// total ~60.4 MB (proven OK)

__device__ __forceinline__ float b2f(uint16_t u) {
    union { uint32_t i; float f; } v; v.i = ((uint32_t)u) << 16; return v.f;
}
__device__ __forceinline__ uint16_t f2b(float f) {
    union { float f; uint32_t i; } v; v.f = f;
    uint32_t x = v.i;
    return (uint16_t)((x + 0x7FFFu + ((x >> 16) & 1u)) >> 16);   // RNE
}
__device__ __forceinline__ void gload_lds16(const void* g, void* l) {
    __builtin_amdgcn_global_load_lds((const __attribute__((address_space(1))) uint32_t*)g,
                                     (__attribute__((address_space(3))) uint32_t*)l,
                                     16, 0, 0);
}

// zero cursor + gbuf; count init = 1 (pre-counts the self-loop edge per node)
__global__ void zero_ws_kernel(int* __restrict__ cnt, int* __restrict__ cur,
                               float* __restrict__ gbuf) {
    int i = blockIdx.x * 256 + threadIdx.x;
    if (i < N_NODES) { cnt[i] = 1; cur[i] = 0; }
    else {
        int j = i - N_NODES;
        if (j < NGRAPH * F) gbuf[j] = 0.f;
    }
}

// ---------------- int64/int32 detect + convert, fused with dst histogram ----
__global__ void cvt_idx_kernel(const int* __restrict__ raw_ei, const int* __restrict__ raw_batch,
                               int* __restrict__ ei32, int* __restrict__ b32,
                               int* __restrict__ count) {
    int i = blockIdx.x * 256 + threadIdx.x;
    int is64 = ((raw_ei[1] | raw_ei[3] | raw_ei[5] | raw_ei[7] |
                 raw_ei[9] | raw_ei[11] | raw_ei[13] | raw_ei[15]) == 0) ? 1 : 0;
    if (i < 2 * N_EDGES) {
        int v = is64 ? raw_ei[2 * i] : raw_ei[i];
        ei32[i] = v;
        if (i >= N_EDGES) atomicAdd(&count[v], 1);   // v is a dst node id
    } else {
        int j = i - 2 * N_EDGES;
        if (j < N_NODES) b32[j] = is64 ? raw_batch[2 * j] : raw_batch[j];
    }
}

// ---------------- all weights fp32 -> bf16 transposed, one kernel -----------
// seg0: W0 [79->128 pad], seg1: W1, seg2: W2 (both K=KP=512)
__global__ void transpose_all_kernel(const float* __restrict__ W0, const float* __restrict__ W1,
                                     const float* __restrict__ W2,
                                     uint16_t* __restrict__ wt0, uint16_t* __restrict__ wt1,
                                     uint16_t* __restrict__ wt2) {
    int i = blockIdx.x * 256 + threadIdx.x;
    if (i < F * 128) {
        int n = i >> 7, k = i & 127;
        wt0[i] = (k < 79) ? f2b(W0[(size_t)k * F + n]) : (uint16_t)0;
    } else if (i < F * 128 + F * F) {
        int j = i - F * 128;
        int n = j >> 9, k = j & 511;
        wt1[j] = f2b(W1[(size_t)k * F + n]);
    } else if (i < F * 128 + 2 * F * F) {
        int j = i - F * 128 - F * F;
        int n = j >> 9, k = j & 511;
        wt2[j] = f2b(W2[(size_t)k * F + n]);
    }
}

// ---------------- MFMA GEMM: C[M_PAD][512] = A[..][K] * Wt[512][KP]^T -------
template <bool AF32>
__global__ __launch_bounds__(256) void gemm_mfma_kernel(
    const void* __restrict__ Av, const uint16_t* __restrict__ Bt,
    uint16_t* __restrict__ C, int M, int K, int KP)
{
    __shared__ uint16_t Alds[128 * 64];
    __shared__ uint16_t Blds[128 * 64];

    const int tid = threadIdx.x;
    const int w = tid >> 6, l = tid & 63;
    const int wr = w >> 1, wc = w & 1;
    const int m0 = blockIdx.x * 128, n0 = blockIdx.y * 128;

    f32x4 acc[4][4];
#pragma unroll
    for (int m = 0; m < 4; ++m)
#pragma unroll
        for (int n = 0; n < 4; ++n) acc[m][n] = (f32x4){0.f, 0.f, 0.f, 0.f};

    const int row_s = (l >> 3);
    const int kof_s = (l & 7) * 8;

    for (int k0 = 0; k0 < KP; k0 += 64) {
        if (AF32) {
            uint4 ta[4];
#pragma unroll
            for (int i = 0; i < 4; ++i) {
                int c = w * 4 + i;
                int ar = m0 + c * 8 + row_s;
                union { uint16_t u[8]; uint4 v; } tmp;
#pragma unroll
                for (int j = 0; j < 8; ++j) {
                    int k = k0 + kof_s + j;
                    float fv = (ar < M && k < K) ? ((const float*)Av)[(size_t)ar * K + k] : 0.f;
                    tmp.u[j] = f2b(fv);
                }
                ta[i] = tmp.v;
            }
            __syncthreads();
#pragma unroll
            for (int i = 0; i < 4; ++i) {
                int c = w * 4 + i;
                *(uint4*)&Alds[c * 512 + l * 8] = ta[i];
                gload_lds16(Bt + (size_t)(n0 + c * 8 + row_s) * KP + k0 + kof_s, &Blds[c * 512]);
            }
            __syncthreads();
        } else {
            __syncthreads();
#pragma unroll
            for (int i = 0; i < 4; ++i) {
                int c = w * 4 + i;                    // chunk 0..15 (wave-uniform LDS base)
                int trow = c * 8 + row_s;             // per-lane global row
                gload_lds16((const uint16_t*)Av + (size_t)(m0 + trow) * K + k0 + kof_s, &Alds[c * 512]);
                gload_lds16(Bt + (size_t)(n0 + trow) * KP + k0 + kof_s, &Blds[c * 512]);
            }
            __syncthreads();
        }
#pragma unroll
        for (int kk = 0; kk < 2; ++kk) {
            const int koff = kk * 32 + (l >> 4) * 8;
            bf16x8 af[4], bfr[4];
#pragma unroll
            for (int m = 0; m < 4; ++m) {
                int row = wr * 64 + m * 16 + (l & 15);
                af[m] = *(const bf16x8*)&Alds[row * 64 + koff];
            }
#pragma unroll
            for (int n = 0; n < 4; ++n) {
                int col = wc * 64 + n * 16 + (l & 15);
                bfr[n] = *(const bf16x8*)&Blds[col * 64 + koff];
            }
#pragma unroll
            for (int m = 0; m < 4; ++m)
#pragma unroll
                for (int n = 0; n < 4; ++n)
                    acc[m][n] = __builtin_amdgcn_mfma_f32_16x16x32_bf16(af[m], bfr[n], acc[m][n], 0, 0, 0);
        }
    }

    // C/D layout (m89-verified): col = lane&15, row = (lane>>4)*4 + j
#pragma unroll
    for (int m = 0; m < 4; ++m) {
        int rb = m0 + wr * 64 + m * 16 + ((l >> 4) << 2);
#pragma unroll
        for (int n = 0; n < 4; ++n) {
            int col = n0 + wc * 64 + n * 16 + (l & 15);
#pragma unroll
            for (int j = 0; j < 4; ++j)
                C[(size_t)(rb + j) * F + col] = f2b(acc[m][n][j]);
        }
    }
}

// ---------------- per-node attention logits ----------------
__global__ void alpha_kernel(const uint16_t* __restrict__ h,
                             const float* __restrict__ asrc, const float* __restrict__ adst,
                             float* __restrict__ als, float* __restrict__ ald)
{
    int gt = blockIdx.x * 256 + threadIdx.x;
    int wv = gt >> 6, l = threadIdx.x & 63;
    if (wv >= N_NODES) return;
    const uint4 hv = *(const uint4*)(h + (size_t)wv * F + l * 8);
    uint32_t hw[4] = {hv.x, hv.y, hv.z, hv.w};
    float hf[8];
#pragma unroll
    for (int j = 0; j < 4; ++j) {
        hf[2 * j]     = b2f((uint16_t)(hw[j] & 0xFFFF));
        hf[2 * j + 1] = b2f((uint16_t)(hw[j] >> 16));
    }
    float ps = 0.f, pd = 0.f;
#pragma unroll
    for (int j = 0; j < 8; ++j) {
        ps += hf[j] * asrc[l * 8 + j];
        pd += hf[j] * adst[l * 8 + j];
    }
#pragma unroll
    for (int s = 1; s < 8; s <<= 1) {
        ps += __shfl_xor(ps, s, 64);
        pd += __shfl_xor(pd, s, 64);
    }
    if ((l & 7) == 0) {
        int hd = l >> 3;
        als[(size_t)wv * 8 + hd] = ps;
        ald[(size_t)wv * 8 + hd] = pd;
    }
}

// ---------------- CSR build (hist now fused into cvt_idx) ----------------
__global__ void scan1_kernel(const int* __restrict__ count, int* __restrict__ rp, int* __restrict__ btot) {
    __shared__ int s[256];
    int t = threadIdx.x, i = blockIdx.x * 256 + t;
    int v = (i < N_NODES) ? count[i] : 0;
    s[t] = v; __syncthreads();
    for (int off = 1; off < 256; off <<= 1) {
        int x = (t >= off) ? s[t - off] : 0; __syncthreads();
        s[t] += x; __syncthreads();
    }
    if (i < N_NODES) rp[i] = s[t] - v;
    if (t == 255) btot[blockIdx.x] = s[255];
}

__global__ void scan2_kernel(int* __restrict__ btot, int* __restrict__ boff) {
    __shared__ int s[128];
    int t = threadIdx.x;
    int v = (t < 79) ? btot[t] : 0;
    s[t] = v; __syncthreads();
    for (int off = 1; off < 128; off <<= 1) {
        int x = (t >= off) ? s[t - off] : 0; __syncthreads();
        s[t] += x; __syncthreads();
    }
    if (t < 79) boff[t] = s[t] - v;
}

__global__ void scan3_kernel(int* __restrict__ rp, const int* __restrict__ boff) {
    int i = blockIdx.x * 256 + threadIdx.x;
    if (i >= N_NODES) return;
    rp[i] += boff[i >> 8];
    if (i == 0) rp[N_NODES] = E_TOT;
}

// store src AND dst node id per CSR slot
__global__ void scatter_kernel(const int* __restrict__ ei, const int* __restrict__ rp,
                               int* __restrict__ cursor, int* __restrict__ csrc,
                               int* __restrict__ cdst) {
    int e = blockIdx.x * 256 + threadIdx.x;
    if (e >= E_TOT) return;
    int src, dst;
    if (e < N_EDGES) { src = ei[e]; dst = ei[N_EDGES + e]; }
    else { src = dst = e - N_EDGES; }
    int pos = atomicAdd(&cursor[dst], 1);
    csrc[rp[dst] + pos] = src;
    cdst[rp[dst] + pos] = dst;
}

// ---------------- per-slot edge weights: ew = exp(leakyrelu(als[s]+ald[d])) --
__global__ void ew_kernel(const int* __restrict__ csrc, const int* __restrict__ cdst,
                          const float* __restrict__ als, const float* __restrict__ ald,
                          float* __restrict__ ew)
{
    int i = blockIdx.x * 256 + threadIdx.x;
    if (i >= E_TOT) return;
    int s = csrc[i], d = cdst[i];
    float4 a0 = *(const float4*)(als + (size_t)s * 8);
    float4 a1 = *(const float4*)(als + (size_t)s * 8 + 4);
    float4 d0 = *(const float4*)(ald + (size_t)d * 8);
    float4 d1 = *(const float4*)(ald + (size_t)d * 8 + 4);
    float v[8] = {a0.x + d0.x, a0.y + d0.y, a0.z + d0.z, a0.w + d0.w,
                  a1.x + d1.x, a1.y + d1.y, a1.z + d1.z, a1.w + d1.w};
#pragma unroll
    for (int hh = 0; hh < 8; ++hh) {
        float xg = v[hh];
        xg = (xg > 0.f) ? xg : NEG_SLOPE * xg;
        v[hh] = __expf(xg);
    }
    float4* o = (float4*)(ew + (size_t)i * 8);
    o[0] = make_float4(v[0], v[1], v[2], v[3]);
    o[1] = make_float4(v[4], v[5], v[6], v[7]);
}

// -------- aggregation (round-11 proven config: 1 node/block, uint32, unroll 8)
__global__ __launch_bounds__(256) void agg_kernel(
    const uint16_t* __restrict__ h,
    const int* __restrict__ rp, const int* __restrict__ csrc,
    const float* __restrict__ ew,
    const float* __restrict__ bias, uint16_t* __restrict__ out)
{
    int n = blockIdx.x, t = threadIdx.x;
    int c0 = t * 2, hd = t >> 5;        // head = c0>>6
    int rs = rp[n], re = rp[n + 1];
    float a0 = 0.f, a1 = 0.f, dsum = 0.f;
    int idx = rs;
    for (; idx + 8 <= re; idx += 8) {
        int s[8]; float w[8]; uint32_t v[8];
#pragma unroll
        for (int j = 0; j < 8; ++j) s[j] = csrc[idx + j];
#pragma unroll
        for (int j = 0; j < 8; ++j) w[j] = ew[(size_t)(idx + j) * 8 + hd];
#pragma unroll
        for (int j = 0; j < 8; ++j) v[j] = *(const uint32_t*)(h + (size_t)s[j] * F + c0);
#pragma unroll
        for (int j = 0; j < 8; ++j) {
            dsum += w[j];
            a0 += w[j] * b2f((uint16_t)(v[j] & 0xFFFF));
            a1 += w[j] * b2f((uint16_t)(v[j] >> 16));
        }
    }
    if (idx + 4 <= re) {
        int s[4]; float w[4]; uint32_t v[4];
#pragma unroll
        for (int j = 0; j < 4; ++j) s[j] = csrc[idx + j];
#pragma unroll
        for (int j = 0; j < 4; ++j) w[j] = ew[(size_t)(idx + j) * 8 + hd];
#pragma unroll
        for (int j = 0; j < 4; ++j) v[j] = *(const uint32_t*)(h + (size_t)s[j] * F + c0);
#pragma unroll
        for (int j = 0; j < 4; ++j) {
            dsum += w[j];
            a0 += w[j] * b2f((uint16_t)(v[j] & 0xFFFF));
            a1 += w[j] * b2f((uint16_t)(v[j] >> 16));
        }
        idx += 4;
    }
    for (; idx < re; ++idx) {
        int s = csrc[idx];
        float wgt = ew[(size_t)idx * 8 + hd];
        dsum += wgt;
        uint32_t hv = *(const uint32_t*)(h + (size_t)s * F + c0);
        a0 += wgt * b2f((uint16_t)(hv & 0xFFFF));
        a1 += wgt * b2f((uint16_t)(hv >> 16));
    }
    float inv = 1.0f / dsum;
    float o0 = a0 * inv + bias[c0];
    float o1 = a1 * inv + bias[c0 + 1];
    o0 = o0 > 0.f ? o0 : 0.f;
    o1 = o1 > 0.f ? o1 : 0.f;
    uint32_t pk = (uint32_t)f2b(o0) | ((uint32_t)f2b(o1) << 16);
    *(uint32_t*)(out + (size_t)n * F + c0) = pk;
}

// ---------------- pooling (grid (NGRAPH, 8) + atomics) ----------------
__device__ __forceinline__ int lbound(const int* arr, int n, int key) {
    int lo = 0, hi = n;
    while (lo < hi) { int mid = (lo + hi) >> 1; if (arr[mid] < key) lo = mid + 1; else hi = mid; }
    return lo;
}

__global__ __launch_bounds__(256) void pool_kernel(
    const uint16_t* __restrict__ h, const int* __restrict__ batch,
    float* __restrict__ g)
{
    int gr = blockIdx.x, chunk = blockIdx.y, t = threadIdx.x;
    int s = lbound(batch, N_NODES, gr);
    int e = lbound(batch, N_NODES, gr + 1);
    int len = e - s;
    int cs = s + (len * chunk) / 8;
    int ce = s + (len * (chunk + 1)) / 8;
    if (cs >= ce) return;
    int c0 = t * 2;
    float a0 = 0.f, a1 = 0.f;
    for (int n = cs; n < ce; ++n) {
        uint32_t hv = *(const uint32_t*)(h + (size_t)n * F + c0);
        a0 += b2f((uint16_t)(hv & 0xFFFF));
        a1 += b2f((uint16_t)(hv >> 16));
    }
    atomicAdd(&g[(size_t)gr * F + c0], a0);
    atomicAdd(&g[(size_t)gr * F + c0 + 1], a1);
}

__global__ void mlp_kernel(
    const float* __restrict__ g,
    const float* __restrict__ l1w, const float* __restrict__ l1b,
    const float* __restrict__ l2w, const float* __restrict__ l2b,
    float* __restrict__ out)
{
    __shared__ float gr[512];
    int b = blockIdx.x, t = threadIdx.x;
    for (int i = t; i < 512; i += 64) gr[i] = g[(size_t)b * F + i];
    __syncthreads();
    float acc = l1b[t];
    for (int k = 0; k < 512; ++k) acc += gr[k] * l1w[k * 64 + t];
    acc = acc > 0.f ? acc : 0.f;
    float v = acc * l2w[t];
#pragma unroll
    for (int s = 1; s < 64; s <<= 1) v += __shfl_xor(v, s, 64);
    if (t == 0) out[b] = v + l2b[0];
}

// ---------------- host ----------------
extern "C" void kernel_launch(void* const* d_in, const int* in_sizes, int n_in,
                              void* d_out, int out_size, void* d_ws, size_t ws_size,
                              hipStream_t stream) {
    const float* x   = (const float*)d_in[0];
    const float* W0  = (const float*)d_in[1];
    const float* as0 = (const float*)d_in[2];
    const float* ad0 = (const float*)d_in[3];
    const float* b0  = (const float*)d_in[4];
    const float* W1  = (const float*)d_in[5];
    const float* as1 = (const float*)d_in[6];
    const float* ad1 = (const float*)d_in[7];
    const float* b1  = (const float*)d_in[8];
    const float* W2  = (const float*)d_in[9];
    const float* as2 = (const float*)d_in[10];
    const float* ad2 = (const float*)d_in[11];
    const float* b2  = (const float*)d_in[12];
    const float* l1w = (const float*)d_in[13];
    const float* l1b = (const float*)d_in[14];
    const float* l2w = (const float*)d_in[15];
    const float* l2b = (const float*)d_in[16];
    const int* ei_raw    = (const int*)d_in[17];
    const int* batch_raw = (const int*)d_in[18];

    char* ws = (char*)d_ws;
    uint16_t* wt0  = (uint16_t*)(ws + WS_WT0);
    uint16_t* wt1  = (uint16_t*)(ws + WS_WT1);
    uint16_t* wt2  = (uint16_t*)(ws + WS_WT2);
    uint16_t* hmid = (uint16_t*)(ws + WS_HMID);
    uint16_t* hA   = (uint16_t*)(ws + WS_HA);
    float* als  = (float*)(ws + WS_ALS);
    float* ald  = (float*)(ws + WS_ALD);
    int* count  = (int*)(ws + WS_CNT);
    int* cursor = (int*)(ws + WS_CUR);
    int* rp     = (int*)(ws + WS_RP);
    int* btot   = (int*)(ws + WS_BTOT);
    int* boff   = (int*)(ws + WS_BOFF);
    int* csrc   = (int*)(ws + WS_CSRC);
    float* gbuf = (float*)(ws + WS_G);
    int* ei32   = (int*)(ws + WS_EI32);
    int* b32    = (int*)(ws + WS_B32);
    int* cdst   = (int*)(ws + WS_CDST);
    float* ew   = (float*)(ws + WS_EW);
    float* out  = (float*)d_out;

    zero_ws_kernel<<<(N_NODES + NGRAPH * F + 255) / 256, 256, 0, stream>>>(count, cursor, gbuf);
    cvt_idx_kernel<<<(2 * N_EDGES + N_NODES + 255) / 256, 256, 0, stream>>>(ei_raw, batch_raw, ei32, b32, count);
    transpose_all_kernel<<<(F * 128 + 2 * F * F + 255) / 256, 256, 0, stream>>>(W0, W1, W2, wt0, wt1, wt2);

    // CSR (structure fixed across layers)
    int eb = (E_TOT + 255) / 256;
    scan1_kernel<<<79, 256, 0, stream>>>(count, rp, btot);
    scan2_kernel<<<1, 128, 0, stream>>>(btot, boff);
    scan3_kernel<<<79, 256, 0, stream>>>(rp, boff);
    scatter_kernel<<<eb, 256, 0, stream>>>(ei32, rp, cursor, csrc, cdst);

    dim3 gg(M_PAD / 128, F / 128);

    // layer 0 (fp32 x, K=79 padded to 128)
    gemm_mfma_kernel<true><<<gg, 256, 0, stream>>>(x, wt0, hmid, N_NODES, 79, 128);
    alpha_kernel<<<(N_NODES * 64) / 256, 256, 0, stream>>>(hmid, as0, ad0, als, ald);
    ew_kernel<<<eb, 256, 0, stream>>>(csrc, cdst, als, ald, ew);
    agg_kernel<<<N_NODES, 256, 0, stream>>>(hmid, rp, csrc, ew, b0, hA);

    // layer 1
    gemm_mfma_kernel<false><<<gg, 256, 0, stream>>>(hA, wt1, hmid, M_PAD, F, F);
    alpha_kernel<<<(N_NODES * 64) / 256, 256, 0, stream>>>(hmid, as1, ad1, als, ald);
    ew_kernel<<<eb, 256, 0, stream>>>(csrc, cdst, als, ald, ew);
    agg_kernel<<<N_NODES, 256, 0, stream>>>(hmid, rp, csrc, ew, b1, hA);

    // layer 2
    gemm_mfma_kernel<false><<<gg, 256, 0, stream>>>(hA, wt2, hmid, M_PAD, F, F);
    alpha_kernel<<<(N_NODES * 64) / 256, 256, 0, stream>>>(hmid, as2, ad2, als, ald);
    ew_kernel<<<eb, 256, 0, stream>>>(csrc, cdst, als, ald, ew);
    agg_kernel<<<N_NODES, 256, 0, stream>>>(hmid, rp, csrc, ew, b2, hA);

    dim3 gp(NGRAPH, 8);
    pool_kernel<<<gp, 256, 0, stream>>>(hA, b32, gbuf);
    mlp_kernel<<<NGRAPH, 64, 0, stream>>>(gbuf, l1w, l1b, l2w, l2b, out);
}